// Round 1
// baseline (425.493 us; speedup 1.0000x reference)
//
#include <hip/hip_runtime.h>

typedef __attribute__((ext_vector_type(4))) float f32x4;
typedef __attribute__((ext_vector_type(8))) __bf16 bf16x8;

constexpr int FD = 128;   // feature dim D = H = 128

__device__ __forceinline__ unsigned short f2bf(float f) {
  union { float f; unsigned int u; } v; v.f = f;
  unsigned int u = v.u;
  return (unsigned short)((u + 0x7fffu + ((u >> 16) & 1u)) >> 16);  // RNE
}

// Pack a (K,128) f32 weight matrix into MFMA B-fragment order, bf16:
// dst[((nt*KS + ks)*64 + lane)*8 + e] = W[k][n]
//   nt = n>>4, ks = k>>5, lane = ((k>>3)&3)*16 + (n&15), e = k&7
__global__ void pack_weights(const float* __restrict__ mw0, const float* __restrict__ mw1,
                             const float* __restrict__ mw2, const float* __restrict__ uw0,
                             const float* __restrict__ uw1, const float* __restrict__ uw2,
                             unsigned short* __restrict__ wp) {
  int tid = blockIdx.x * 256 + threadIdx.x;   // 576*256 == 147456 exactly
  const float* src; int base, K;
  if      (tid < 49152)  { src = mw0; base = 0;      K = 384; }
  else if (tid < 65536)  { src = mw1; base = 49152;  K = 128; }
  else if (tid < 81920)  { src = mw2; base = 65536;  K = 128; }
  else if (tid < 114688) { src = uw0; base = 81920;  K = 256; }
  else if (tid < 131072) { src = uw1; base = 114688; K = 128; }
  else                   { src = uw2; base = 131072; K = 128; }
  int i = tid - base;
  int k = i >> 7, n = i & 127;
  int KS = K >> 5;
  int dst = base + (((n >> 4) * KS + (k >> 5)) * 64 + ((k >> 3) & 3) * 16 + (n & 15)) * 8 + (k & 7);
  wp[dst] = f2bf(src[i]);
}

// One MLP layer on a 64-row tile: acc[4] (f32x4) += A[64xK](LDS bf16) @ Wpacked[Kx128].
// Weight K=32 slices staged through sW (8KB) with barrier sync; global load issued
// pre-barrier so its latency overlaps the previous slice's MFMAs.
template<int KSTEPS>
__device__ __forceinline__ void mfma_layer(
    const unsigned short* __restrict__ wsrc,
    const unsigned short* sAsrc, int strideA,
    unsigned short* sW, f32x4* acc,
    int w, int lane, int m0, int c0hi, int g16, int ln) {
  for (int ks = 0; ks < KSTEPS; ++ks) {
    // prefetch this wave's 16B chunk of the slice (nt = w)
    uint4 u = *(const uint4*)(wsrc + (size_t)((w * KSTEPS + ks) * 64 + lane) * 8);
    __syncthreads();                                   // prev slice fully consumed
    *(uint4*)&sW[(size_t)threadIdx.x * 8] = u;
    __syncthreads();                                   // slice visible
    bf16x8 a = *(const bf16x8*)&sAsrc[(m0 + ln) * strideA + ks * 32 + g16 * 8];
#pragma unroll
    for (int nf = 0; nf < 4; ++nf) {
      bf16x8 b = *(const bf16x8*)&sW[((c0hi + nf) * 64 + lane) * 8];
      acc[nf] = __builtin_amdgcn_mfma_f32_16x16x32_bf16(a, b, acc[nf], 0, 0, 0);
    }
  }
}

// Edge kernel: 64 edges/block, 512 threads (8 waves: 4 row-groups x 2 col-groups).
// concat=[x_dst | x_src | edge_attr] -> MLP(384->128->128->128) -> LN -> +edge_attr
// -> atomicAdd into agg[dst].
__global__ __launch_bounds__(512, 4)
void in_edge_kernel(const float* __restrict__ node_x, const float* __restrict__ edge_attr,
                    const int* __restrict__ eidx, const unsigned short* __restrict__ wp,
                    const float* __restrict__ b0p, const float* __restrict__ b1p,
                    const float* __restrict__ b2p, const float* __restrict__ gp,
                    const float* __restrict__ bep, float* __restrict__ agg, int E) {
  __shared__ unsigned short sA[64 * 392];   // concat tile bf16, row stride 392 (16B-aligned, 2-way banks)
  __shared__ unsigned short sW[4096];       // 8KB weight slice
  __shared__ unsigned short sC[64 * 136];   // relu(h) tile bf16, stride 136
  __shared__ int sSrc[64], sDst[64];
  __shared__ float sRed[64][2][2];          // per-row (sum, sumsq) per col-half

  const int t = threadIdx.x;
  const int e0 = blockIdx.x * 64;

  if (t < 64)       sSrc[t] = (e0 + t < E) ? eidx[e0 + t] : 0;
  else if (t < 128) sDst[t - 64] = (e0 + t - 64 < E) ? eidx[E + e0 + t - 64] : 0;
  __syncthreads();

  // stage concat tile: 64 rows x 384 cols, as 6144 float4 over 512 threads
#pragma unroll
  for (int i = 0; i < 12; ++i) {
    int f = t + i * 512;
    int row = f / 96;
    int c4 = (f - row * 96) * 4;
    f32x4 v = {0.f, 0.f, 0.f, 0.f};
    if (e0 + row < E) {
      const float* sp;
      if (c4 < 128)      sp = node_x + (size_t)sDst[row] * FD + c4;         // x_i = x[dst]
      else if (c4 < 256) sp = node_x + (size_t)sSrc[row] * FD + (c4 - 128); // x_j = x[src]
      else               sp = edge_attr + (size_t)(e0 + row) * FD + (c4 - 256);
      v = *(const f32x4*)sp;
    }
    ushort4 o;
    o.x = f2bf(v[0]); o.y = f2bf(v[1]); o.z = f2bf(v[2]); o.w = f2bf(v[3]);
    *(ushort4*)&sA[row * 392 + c4] = o;
  }
  // (no barrier needed: mfma_layer's first __syncthreads covers staging visibility)

  const int w = t >> 6, lane = t & 63;
  const int m0 = (w & 3) * 16;        // row-group base
  const int c0hi = (w >> 2) * 4;      // nt base (col-group * 4)
  const int c0 = c0hi * 16;
  const int g16 = lane >> 4, ln = lane & 15;

  float b0v[4], b1v[4], b2v[4], gv[4], bev[4];
#pragma unroll
  for (int nf = 0; nf < 4; ++nf) {
    int col = c0 + nf * 16 + ln;
    b0v[nf] = b0p[col]; b1v[nf] = b1p[col]; b2v[nf] = b2p[col];
    gv[nf] = gp[col];   bev[nf] = bep[col];
  }

  f32x4 acc[4];
#pragma unroll
  for (int nf = 0; nf < 4; ++nf) acc[nf] = (f32x4){0.f, 0.f, 0.f, 0.f};

  mfma_layer<12>(wp, sA, 392, sW, acc, w, lane, m0, c0hi, g16, ln);

  // C0 = relu(h0 + b0) -> sC (bf16)
#pragma unroll
  for (int nf = 0; nf < 4; ++nf)
#pragma unroll
    for (int ri = 0; ri < 4; ++ri) {
      float v = acc[nf][ri] + b0v[nf];
      sC[(m0 + g16 * 4 + ri) * 136 + c0 + nf * 16 + ln] = f2bf(fmaxf(v, 0.f));
      acc[nf][ri] = 0.f;
    }

  mfma_layer<4>(wp + 49152, sC, 136, sW, acc, w, lane, m0, c0hi, g16, ln);

  unsigned short* sC1 = sA;   // sA is dead after L0 -> reuse for C1
#pragma unroll
  for (int nf = 0; nf < 4; ++nf)
#pragma unroll
    for (int ri = 0; ri < 4; ++ri) {
      float v = acc[nf][ri] + b1v[nf];
      sC1[(m0 + g16 * 4 + ri) * 136 + c0 + nf * 16 + ln] = f2bf(fmaxf(v, 0.f));
      acc[nf][ri] = 0.f;
    }

  mfma_layer<4>(wp + 65536, sC1, 136, sW, acc, w, lane, m0, c0hi, g16, ln);

  // LayerNorm across the 128 cols of each row (split over 2 col-group waves)
  float r1[4], r2[4];
#pragma unroll
  for (int ri = 0; ri < 4; ++ri) {
    float s1 = 0.f, s2 = 0.f;
#pragma unroll
    for (int nf = 0; nf < 4; ++nf) {
      float h = acc[nf][ri] + b2v[nf];
      s1 += h; s2 += h * h;
    }
#pragma unroll
    for (int m = 1; m < 16; m <<= 1) {   // reduce over the 16 lanes sharing these rows
      s1 += __shfl_xor(s1, m, 64);
      s2 += __shfl_xor(s2, m, 64);
    }
    r1[ri] = s1; r2[ri] = s2;
  }
  if (ln == 0) {
#pragma unroll
    for (int ri = 0; ri < 4; ++ri) {
      sRed[m0 + g16 * 4 + ri][w >> 2][0] = r1[ri];
      sRed[m0 + g16 * 4 + ri][w >> 2][1] = r2[ri];
    }
  }
  __syncthreads();
#pragma unroll
  for (int ri = 0; ri < 4; ++ri) {
    int row = m0 + g16 * 4 + ri;
    int e = e0 + row;
    if (e >= E) continue;
    float t1 = sRed[row][0][0] + sRed[row][1][0];
    float t2 = sRed[row][0][1] + sRed[row][1][1];
    float mean = t1 * (1.f / 128.f);
    float var  = t2 * (1.f / 128.f) - mean * mean;
    float rstd = rsqrtf(fmaxf(var, 0.f) + 1e-5f);
    int dn = sDst[row];
#pragma unroll
    for (int nf = 0; nf < 4; ++nf) {
      int col = c0 + nf * 16 + ln;
      float h = acc[nf][ri] + b2v[nf];
      float val = (h - mean) * rstd * gv[nf] + bev[nf] + edge_attr[(size_t)e * FD + col];
      atomicAdd(agg + (size_t)dn * FD + col, val);
    }
  }
}

// Node kernel: 64 nodes/block; concat2=[node_x | agg] -> MLP(256->128->128->128)
// -> LN -> + node_x -> out.
__global__ __launch_bounds__(512, 4)
void in_node_kernel(const float* __restrict__ node_x, const float* __restrict__ agg,
                    const unsigned short* __restrict__ wp,
                    const float* __restrict__ b0p, const float* __restrict__ b1p,
                    const float* __restrict__ b2p, const float* __restrict__ gp,
                    const float* __restrict__ bep, float* __restrict__ out, int N) {
  __shared__ unsigned short sA[64 * 264];   // concat2 tile bf16, stride 264
  __shared__ unsigned short sW[4096];
  __shared__ unsigned short sC[64 * 136];
  __shared__ float sRed[64][2][2];

  const int t = threadIdx.x;
  const int r0 = blockIdx.x * 64;

#pragma unroll
  for (int i = 0; i < 8; ++i) {            // 4096 float4
    int f = t + i * 512;
    int row = f >> 6;
    int c4 = (f & 63) * 4;
    f32x4 v = {0.f, 0.f, 0.f, 0.f};
    int r = r0 + row;
    if (r < N) {
      const float* sp = (c4 < 128) ? node_x + (size_t)r * FD + c4
                                   : agg + (size_t)r * FD + (c4 - 128);
      v = *(const f32x4*)sp;
    }
    ushort4 o;
    o.x = f2bf(v[0]); o.y = f2bf(v[1]); o.z = f2bf(v[2]); o.w = f2bf(v[3]);
    *(ushort4*)&sA[row * 264 + c4] = o;
  }

  const int w = t >> 6, lane = t & 63;
  const int m0 = (w & 3) * 16;
  const int c0hi = (w >> 2) * 4;
  const int c0 = c0hi * 16;
  const int g16 = lane >> 4, ln = lane & 15;

  float b0v[4], b1v[4], b2v[4], gv[4], bev[4];
#pragma unroll
  for (int nf = 0; nf < 4; ++nf) {
    int col = c0 + nf * 16 + ln;
    b0v[nf] = b0p[col]; b1v[nf] = b1p[col]; b2v[nf] = b2p[col];
    gv[nf] = gp[col];   bev[nf] = bep[col];
  }

  f32x4 acc[4];
#pragma unroll
  for (int nf = 0; nf < 4; ++nf) acc[nf] = (f32x4){0.f, 0.f, 0.f, 0.f};

  mfma_layer<8>(wp + 81920, sA, 264, sW, acc, w, lane, m0, c0hi, g16, ln);

#pragma unroll
  for (int nf = 0; nf < 4; ++nf)
#pragma unroll
    for (int ri = 0; ri < 4; ++ri) {
      float v = acc[nf][ri] + b0v[nf];
      sC[(m0 + g16 * 4 + ri) * 136 + c0 + nf * 16 + ln] = f2bf(fmaxf(v, 0.f));
      acc[nf][ri] = 0.f;
    }

  mfma_layer<4>(wp + 114688, sC, 136, sW, acc, w, lane, m0, c0hi, g16, ln);

  unsigned short* sC1 = sA;
#pragma unroll
  for (int nf = 0; nf < 4; ++nf)
#pragma unroll
    for (int ri = 0; ri < 4; ++ri) {
      float v = acc[nf][ri] + b1v[nf];
      sC1[(m0 + g16 * 4 + ri) * 136 + c0 + nf * 16 + ln] = f2bf(fmaxf(v, 0.f));
      acc[nf][ri] = 0.f;
    }

  mfma_layer<4>(wp + 131072, sC1, 136, sW, acc, w, lane, m0, c0hi, g16, ln);

  float r1[4], r2[4];
#pragma unroll
  for (int ri = 0; ri < 4; ++ri) {
    float s1 = 0.f, s2 = 0.f;
#pragma unroll
    for (int nf = 0; nf < 4; ++nf) {
      float h = acc[nf][ri] + b2v[nf];
      s1 += h; s2 += h * h;
    }
#pragma unroll
    for (int m = 1; m < 16; m <<= 1) {
      s1 += __shfl_xor(s1, m, 64);
      s2 += __shfl_xor(s2, m, 64);
    }
    r1[ri] = s1; r2[ri] = s2;
  }
  if (ln == 0) {
#pragma unroll
    for (int ri = 0; ri < 4; ++ri) {
      sRed[m0 + g16 * 4 + ri][w >> 2][0] = r1[ri];
      sRed[m0 + g16 * 4 + ri][w >> 2][1] = r2[ri];
    }
  }
  __syncthreads();
#pragma unroll
  for (int ri = 0; ri < 4; ++ri) {
    int row = m0 + g16 * 4 + ri;
    int r = r0 + row;
    if (r >= N) continue;
    float t1 = sRed[row][0][0] + sRed[row][1][0];
    float t2 = sRed[row][0][1] + sRed[row][1][1];
    float mean = t1 * (1.f / 128.f);
    float var  = t2 * (1.f / 128.f) - mean * mean;
    float rstd = rsqrtf(fmaxf(var, 0.f) + 1e-5f);
#pragma unroll
    for (int nf = 0; nf < 4; ++nf) {
      int col = c0 + nf * 16 + ln;
      float h = acc[nf][ri] + b2v[nf];
      out[(size_t)r * FD + col] =
          (h - mean) * rstd * gv[nf] + bev[nf] + node_x[(size_t)r * FD + col];
    }
  }
}

extern "C" void kernel_launch(void* const* d_in, const int* in_sizes, int n_in,
                              void* d_out, int out_size, void* d_ws, size_t ws_size,
                              hipStream_t stream) {
  const float* node_x    = (const float*)d_in[0];
  const float* edge_attr = (const float*)d_in[1];
  const int*   eidx      = (const int*)d_in[2];
  const int N = in_sizes[0] / FD;
  const int E = in_sizes[1] / FD;

  float* agg = (float*)d_ws;                                         // [N][128] f32
  unsigned short* wp = (unsigned short*)((char*)d_ws + (size_t)N * FD * sizeof(float));

  (void)hipMemsetAsync(agg, 0, (size_t)N * FD * sizeof(float), stream);
  pack_weights<<<576, 256, 0, stream>>>(
      (const float*)d_in[3], (const float*)d_in[5], (const float*)d_in[7],
      (const float*)d_in[11], (const float*)d_in[13], (const float*)d_in[15], wp);
  in_edge_kernel<<<(E + 63) / 64, 512, 0, stream>>>(
      node_x, edge_attr, eidx, wp,
      (const float*)d_in[4], (const float*)d_in[6], (const float*)d_in[8],
      (const float*)d_in[9], (const float*)d_in[10], agg, E);
  in_node_kernel<<<(N + 63) / 64, 512, 0, stream>>>(
      node_x, agg, wp,
      (const float*)d_in[12], (const float*)d_in[14], (const float*)d_in[16],
      (const float*)d_in[17], (const float*)d_in[18], (float*)d_out, N);
}

// Round 2
// 395.550 us; speedup vs baseline: 1.0757x; 1.0757x over previous
//
#include <hip/hip_runtime.h>

typedef __attribute__((ext_vector_type(4))) float f32x4;
typedef __attribute__((ext_vector_type(8))) __bf16 bf16x8;

constexpr int FD = 128;   // feature dim D = H = 128

__device__ __forceinline__ unsigned short f2bf(float f) {
  union { float f; unsigned int u; } v; v.f = f;
  unsigned int u = v.u;
  return (unsigned short)((u + 0x7fffu + ((u >> 16) & 1u)) >> 16);  // RNE
}
__device__ __forceinline__ float bf2f(unsigned short b) {
  union { unsigned int u; float f; } v; v.u = ((unsigned int)b) << 16;
  return v.f;
}

// Pack a (K,128) f32 weight matrix into MFMA B-fragment order, bf16:
// dst[((nt*KS + ks)*64 + lane)*8 + e] = W[k][n]
//   nt = n>>4, ks = k>>5, lane = ((k>>3)&3)*16 + (n&15), e = k&7
__global__ void pack_weights(const float* __restrict__ mw0, const float* __restrict__ mw1,
                             const float* __restrict__ mw2, const float* __restrict__ uw0,
                             const float* __restrict__ uw1, const float* __restrict__ uw2,
                             unsigned short* __restrict__ wp) {
  int tid = blockIdx.x * 256 + threadIdx.x;   // 576*256 == 147456 exactly
  const float* src; int base, K;
  if      (tid < 49152)  { src = mw0; base = 0;      K = 384; }
  else if (tid < 65536)  { src = mw1; base = 49152;  K = 128; }
  else if (tid < 81920)  { src = mw2; base = 65536;  K = 128; }
  else if (tid < 114688) { src = uw0; base = 81920;  K = 256; }
  else if (tid < 131072) { src = uw1; base = 114688; K = 128; }
  else                   { src = uw2; base = 131072; K = 128; }
  int i = tid - base;
  int k = i >> 7, n = i & 127;
  int KS = K >> 5;
  int dst = base + (((n >> 4) * KS + (k >> 5)) * 64 + ((k >> 3) & 3) * 16 + (n & 15)) * 8 + (k & 7);
  wp[dst] = f2bf(src[i]);
}

// One MLP layer on a 64-row tile: acc[4] (f32x4) += A[64xK](LDS bf16) @ Wpacked[Kx128].
// B fragments are loaded DIRECTLY from global (weights are 160KB total, shared by
// every block -> permanently L1/L2 resident). No barriers, no LDS weight staging:
// the compiler pipelines the global loads across the fully-unrolled K loop.
template<int KSTEPS>
__device__ __forceinline__ void mfma_layer(
    const unsigned short* __restrict__ wsrc,
    const unsigned short* sAsrc, int strideA, f32x4* acc,
    int lane, int m0, int c0hi, int g16, int ln) {
#pragma unroll
  for (int ks = 0; ks < KSTEPS; ++ks) {
    bf16x8 a = *(const bf16x8*)&sAsrc[(m0 + ln) * strideA + ks * 32 + g16 * 8];
#pragma unroll
    for (int nf = 0; nf < 4; ++nf) {
      bf16x8 b = *(const bf16x8*)(wsrc + (size_t)(((c0hi + nf) * KSTEPS + ks) * 64 + lane) * 8);
      acc[nf] = __builtin_amdgcn_mfma_f32_16x16x32_bf16(a, b, acc[nf], 0, 0, 0);
    }
  }
}

// Edge kernel: 64 edges/block, 512 threads (8 waves: 4 row-groups x 2 col-groups).
// concat=[x_dst | x_src | edge_attr] -> MLP(384->128->128->128) -> LN -> +edge_attr
// -> atomicAdd into agg[dst].
__global__ __launch_bounds__(512, 4)
void in_edge_kernel(const float* __restrict__ node_x, const float* __restrict__ edge_attr,
                    const int* __restrict__ eidx, const unsigned short* __restrict__ wp,
                    const float* __restrict__ b0p, const float* __restrict__ b1p,
                    const float* __restrict__ b2p, const float* __restrict__ gp,
                    const float* __restrict__ bep, float* __restrict__ agg, int E) {
  __shared__ unsigned short sA[64 * 392];   // concat tile bf16; cols 256-383 (edge_attr) stay live
  __shared__ unsigned short sC[64 * 136];   // relu(h) tile bf16, stride 136
  __shared__ int sSrc[64], sDst[64];
  __shared__ float sRed[64][2][2];          // per-row (sum, sumsq) per col-half

  const int t = threadIdx.x;
  const int e0 = blockIdx.x * 64;

  if (t < 64)       sSrc[t] = (e0 + t < E) ? eidx[e0 + t] : 0;
  else if (t < 128) sDst[t - 64] = (e0 + t - 64 < E) ? eidx[E + e0 + t - 64] : 0;
  __syncthreads();

  // stage concat tile: 64 rows x 384 cols, as 6144 float4 over 512 threads
#pragma unroll
  for (int i = 0; i < 12; ++i) {
    int f = t + i * 512;
    int row = f / 96;
    int c4 = (f - row * 96) * 4;
    f32x4 v = {0.f, 0.f, 0.f, 0.f};
    if (e0 + row < E) {
      const float* sp;
      if (c4 < 128)      sp = node_x + (size_t)sDst[row] * FD + c4;         // x_i = x[dst]
      else if (c4 < 256) sp = node_x + (size_t)sSrc[row] * FD + (c4 - 128); // x_j = x[src]
      else               sp = edge_attr + (size_t)(e0 + row) * FD + (c4 - 256);
      v = *(const f32x4*)sp;
    }
    ushort4 o;
    o.x = f2bf(v[0]); o.y = f2bf(v[1]); o.z = f2bf(v[2]); o.w = f2bf(v[3]);
    *(ushort4*)&sA[row * 392 + c4] = o;
  }
  __syncthreads();

  const int w = t >> 6, lane = t & 63;
  const int m0 = (w & 3) * 16;        // row-group base
  const int c0hi = (w >> 2) * 4;      // nt base (col-group * 4)
  const int c0 = c0hi * 16;
  const int g16 = lane >> 4, ln = lane & 15;

  float b0v[4], b1v[4], b2v[4], gv[4], bev[4];
#pragma unroll
  for (int nf = 0; nf < 4; ++nf) {
    int col = c0 + nf * 16 + ln;
    b0v[nf] = b0p[col]; b1v[nf] = b1p[col]; b2v[nf] = b2p[col];
    gv[nf] = gp[col];   bev[nf] = bep[col];
  }

  f32x4 acc[4];
#pragma unroll
  for (int nf = 0; nf < 4; ++nf) acc[nf] = (f32x4){0.f, 0.f, 0.f, 0.f};

  mfma_layer<12>(wp, sA, 392, acc, lane, m0, c0hi, g16, ln);

  // C0 = relu(h0 + b0) -> sC (bf16)
#pragma unroll
  for (int nf = 0; nf < 4; ++nf)
#pragma unroll
    for (int ri = 0; ri < 4; ++ri) {
      float v = acc[nf][ri] + b0v[nf];
      sC[(m0 + g16 * 4 + ri) * 136 + c0 + nf * 16 + ln] = f2bf(fmaxf(v, 0.f));
      acc[nf][ri] = 0.f;
    }
  __syncthreads();   // sC visible; also guarantees all layer-0 sA reads done

  mfma_layer<4>(wp + 49152, sC, 136, acc, lane, m0, c0hi, g16, ln);

  // C1 -> sA cols 0..127 (layer-0 region dead; edge_attr cols 256+ preserved)
#pragma unroll
  for (int nf = 0; nf < 4; ++nf)
#pragma unroll
    for (int ri = 0; ri < 4; ++ri) {
      float v = acc[nf][ri] + b1v[nf];
      sA[(m0 + g16 * 4 + ri) * 392 + c0 + nf * 16 + ln] = f2bf(fmaxf(v, 0.f));
      acc[nf][ri] = 0.f;
    }
  __syncthreads();

  mfma_layer<4>(wp + 65536, sA, 392, acc, lane, m0, c0hi, g16, ln);

  // LayerNorm across the 128 cols of each row (split over 2 col-group waves)
  float r1[4], r2[4];
#pragma unroll
  for (int ri = 0; ri < 4; ++ri) {
    float s1 = 0.f, s2 = 0.f;
#pragma unroll
    for (int nf = 0; nf < 4; ++nf) {
      float h = acc[nf][ri] + b2v[nf];
      s1 += h; s2 += h * h;
    }
#pragma unroll
    for (int m = 1; m < 16; m <<= 1) {   // reduce over the 16 lanes sharing these rows
      s1 += __shfl_xor(s1, m, 64);
      s2 += __shfl_xor(s2, m, 64);
    }
    r1[ri] = s1; r2[ri] = s2;
  }
  if (ln == 0) {
#pragma unroll
    for (int ri = 0; ri < 4; ++ri) {
      sRed[m0 + g16 * 4 + ri][w >> 2][0] = r1[ri];
      sRed[m0 + g16 * 4 + ri][w >> 2][1] = r2[ri];
    }
  }
  __syncthreads();
#pragma unroll
  for (int ri = 0; ri < 4; ++ri) {
    int row = m0 + g16 * 4 + ri;
    int e = e0 + row;
    if (e >= E) continue;
    float t1 = sRed[row][0][0] + sRed[row][1][0];
    float t2 = sRed[row][0][1] + sRed[row][1][1];
    float mean = t1 * (1.f / 128.f);
    float var  = t2 * (1.f / 128.f) - mean * mean;
    float rstd = rsqrtf(fmaxf(var, 0.f) + 1e-5f);
    int dn = sDst[row];
#pragma unroll
    for (int nf = 0; nf < 4; ++nf) {
      int col = c0 + nf * 16 + ln;
      float h = acc[nf][ri] + b2v[nf];
      float ea = bf2f(sA[row * 392 + 256 + col]);   // edge_attr from LDS (bf16)
      float val = (h - mean) * rstd * gv[nf] + bev[nf] + ea;
      atomicAdd(agg + (size_t)dn * FD + col, val);
    }
  }
}

// Node kernel: 64 nodes/block; concat2=[node_x | agg] -> MLP(256->128->128->128)
// -> LN -> + node_x -> out.
__global__ __launch_bounds__(512, 4)
void in_node_kernel(const float* __restrict__ node_x, const float* __restrict__ agg,
                    const unsigned short* __restrict__ wp,
                    const float* __restrict__ b0p, const float* __restrict__ b1p,
                    const float* __restrict__ b2p, const float* __restrict__ gp,
                    const float* __restrict__ bep, float* __restrict__ out, int N) {
  __shared__ unsigned short sA[64 * 264];   // concat2 tile bf16, stride 264
  __shared__ unsigned short sC[64 * 136];
  __shared__ float sRed[64][2][2];

  const int t = threadIdx.x;
  const int r0 = blockIdx.x * 64;

#pragma unroll
  for (int i = 0; i < 8; ++i) {            // 4096 float4
    int f = t + i * 512;
    int row = f >> 6;
    int c4 = (f & 63) * 4;
    f32x4 v = {0.f, 0.f, 0.f, 0.f};
    int r = r0 + row;
    if (r < N) {
      const float* sp = (c4 < 128) ? node_x + (size_t)r * FD + c4
                                   : agg + (size_t)r * FD + (c4 - 128);
      v = *(const f32x4*)sp;
    }
    ushort4 o;
    o.x = f2bf(v[0]); o.y = f2bf(v[1]); o.z = f2bf(v[2]); o.w = f2bf(v[3]);
    *(ushort4*)&sA[row * 264 + c4] = o;
  }
  __syncthreads();

  const int w = t >> 6, lane = t & 63;
  const int m0 = (w & 3) * 16;
  const int c0hi = (w >> 2) * 4;
  const int c0 = c0hi * 16;
  const int g16 = lane >> 4, ln = lane & 15;

  float b0v[4], b1v[4], b2v[4], gv[4], bev[4];
#pragma unroll
  for (int nf = 0; nf < 4; ++nf) {
    int col = c0 + nf * 16 + ln;
    b0v[nf] = b0p[col]; b1v[nf] = b1p[col]; b2v[nf] = b2p[col];
    gv[nf] = gp[col];   bev[nf] = bep[col];
  }

  f32x4 acc[4];
#pragma unroll
  for (int nf = 0; nf < 4; ++nf) acc[nf] = (f32x4){0.f, 0.f, 0.f, 0.f};

  mfma_layer<8>(wp + 81920, sA, 264, acc, lane, m0, c0hi, g16, ln);

#pragma unroll
  for (int nf = 0; nf < 4; ++nf)
#pragma unroll
    for (int ri = 0; ri < 4; ++ri) {
      float v = acc[nf][ri] + b0v[nf];
      sC[(m0 + g16 * 4 + ri) * 136 + c0 + nf * 16 + ln] = f2bf(fmaxf(v, 0.f));
      acc[nf][ri] = 0.f;
    }
  __syncthreads();

  mfma_layer<4>(wp + 114688, sC, 136, acc, lane, m0, c0hi, g16, ln);

  // C1 -> sA cols 0..127 (stride 264); node_x residual re-read from global (L2-hot)
#pragma unroll
  for (int nf = 0; nf < 4; ++nf)
#pragma unroll
    for (int ri = 0; ri < 4; ++ri) {
      float v = acc[nf][ri] + b1v[nf];
      sA[(m0 + g16 * 4 + ri) * 264 + c0 + nf * 16 + ln] = f2bf(fmaxf(v, 0.f));
      acc[nf][ri] = 0.f;
    }
  __syncthreads();

  mfma_layer<4>(wp + 131072, sA, 264, acc, lane, m0, c0hi, g16, ln);

  float r1[4], r2[4];
#pragma unroll
  for (int ri = 0; ri < 4; ++ri) {
    float s1 = 0.f, s2 = 0.f;
#pragma unroll
    for (int nf = 0; nf < 4; ++nf) {
      float h = acc[nf][ri] + b2v[nf];
      s1 += h; s2 += h * h;
    }
#pragma unroll
    for (int m = 1; m < 16; m <<= 1) {
      s1 += __shfl_xor(s1, m, 64);
      s2 += __shfl_xor(s2, m, 64);
    }
    r1[ri] = s1; r2[ri] = s2;
  }
  if (ln == 0) {
#pragma unroll
    for (int ri = 0; ri < 4; ++ri) {
      sRed[m0 + g16 * 4 + ri][w >> 2][0] = r1[ri];
      sRed[m0 + g16 * 4 + ri][w >> 2][1] = r2[ri];
    }
  }
  __syncthreads();
#pragma unroll
  for (int ri = 0; ri < 4; ++ri) {
    int row = m0 + g16 * 4 + ri;
    int r = r0 + row;
    if (r >= N) continue;
    float t1 = sRed[row][0][0] + sRed[row][1][0];
    float t2 = sRed[row][0][1] + sRed[row][1][1];
    float mean = t1 * (1.f / 128.f);
    float var  = t2 * (1.f / 128.f) - mean * mean;
    float rstd = rsqrtf(fmaxf(var, 0.f) + 1e-5f);
#pragma unroll
    for (int nf = 0; nf < 4; ++nf) {
      int col = c0 + nf * 16 + ln;
      float h = acc[nf][ri] + b2v[nf];
      out[(size_t)r * FD + col] =
          (h - mean) * rstd * gv[nf] + bev[nf] + node_x[(size_t)r * FD + col];
    }
  }
}

extern "C" void kernel_launch(void* const* d_in, const int* in_sizes, int n_in,
                              void* d_out, int out_size, void* d_ws, size_t ws_size,
                              hipStream_t stream) {
  const float* node_x    = (const float*)d_in[0];
  const float* edge_attr = (const float*)d_in[1];
  const int*   eidx      = (const int*)d_in[2];
  const int N = in_sizes[0] / FD;
  const int E = in_sizes[1] / FD;

  float* agg = (float*)d_ws;                                         // [N][128] f32
  unsigned short* wp = (unsigned short*)((char*)d_ws + (size_t)N * FD * sizeof(float));

  (void)hipMemsetAsync(agg, 0, (size_t)N * FD * sizeof(float), stream);
  pack_weights<<<576, 256, 0, stream>>>(
      (const float*)d_in[3], (const float*)d_in[5], (const float*)d_in[7],
      (const float*)d_in[11], (const float*)d_in[13], (const float*)d_in[15], wp);
  in_edge_kernel<<<(E + 63) / 64, 512, 0, stream>>>(
      node_x, edge_attr, eidx, wp,
      (const float*)d_in[4], (const float*)d_in[6], (const float*)d_in[8],
      (const float*)d_in[9], (const float*)d_in[10], agg, E);
  in_node_kernel<<<(N + 63) / 64, 512, 0, stream>>>(
      node_x, agg, wp,
      (const float*)d_in[12], (const float*)d_in[14], (const float*)d_in[16],
      (const float*)d_in[17], (const float*)d_in[18], (float*)d_out, N);
}